// Round 4
// baseline (3763.952 us; speedup 1.0000x reference)
//
#include <hip/hip_runtime.h>

// LSTM B=64 T=512 IN=512 H=1024 OUT=512, all fp32 in/out.
// Persistent-RNN: 256 WGs (2 groups x 128), W in VGPRs as fp16 MFMA fragments,
// h double-buffered in ws, agent-coherent (sc0 sc1) h traffic.
// R3 changes (decongest the publication line, pipeline the release):
//   - per-WG flag words (parallel one-way stores) instead of one RMW counter
//   - single poller wave per WG (u64 loads, s_sleep backoff), syncthreads bcast
//   - h-store ack hidden under next step's x-part MFMAs (acc double-buffer)

#define B_   64
#define T_   512
#define IN_  512
#define H_   1024
#define G4_  4096   // 4*H
#define OUT_ 512

typedef _Float16 f16;
typedef _Float16 f16x8 __attribute__((ext_vector_type(8)));
typedef _Float16 f16x4 __attribute__((ext_vector_type(4)));
typedef float f32x4  __attribute__((ext_vector_type(4)));
typedef float f32x16 __attribute__((ext_vector_type(16)));

// workspace layout (bytes)
#define X16_OFF   0UL                         // [64][512][512] f16 = 33554432
#define WOT_OFF   33554432UL                  // W_out^T [512][1024] f16 = 1048576
#define H_OFF     (WOT_OFF + 1048576UL)       // h: [2 grp][2 buf][32][1024] f16 = 262144
#define FLG_OFF   (H_OFF + 262144UL)          // flags: 2 groups x 128 u32 (512B stride)
#define WS_NEED   (FLG_OFF + 2048UL)
#define ZERO_BYTES (262144UL + 2048UL)        // h + flags zeroed together

__device__ __forceinline__ float sigmoidf_(float v) { return 1.f / (1.f + __expf(-v)); }
__device__ __forceinline__ float tanhf_(float v) { return 1.f - 2.f / (__expf(2.f * v) + 1.f); }

// Agent-coherent 16B load: bypasses L1 (sc0) and the non-coherent per-XCD L2
// (sc1); served at the coherent LLC point.
__device__ __forceinline__ f16x8 ld_agent_b128(const f16* p) {
  f16x8 r;
  asm volatile("global_load_dwordx4 %0, %1, off sc0 sc1" : "=v"(r) : "v"(p));
  return r;
}

// Agent-coherent 2B store: write-through to the coherence point.
__device__ __forceinline__ void st_agent_b16(f16* p, f16 v) {
  unsigned int u = (unsigned int)__builtin_bit_cast(unsigned short, v);
  asm volatile("global_store_short %0, %1, off sc0 sc1" :: "v"(p), "v"(u) : "memory");
}

// Wait all outstanding VMEM; fence the scheduler so register-only MFMAs can't
// hoist above the wait (rule #18 hazard class).
__device__ __forceinline__ void wait_vm0() {
  asm volatile("s_waitcnt vmcnt(0)" ::: "memory");
  __builtin_amdgcn_sched_barrier(0);
}

__global__ __launch_bounds__(256) void lstm_prepass(
    const float* __restrict__ x, const float* __restrict__ Wout,
    f16* __restrict__ x16, f16* __restrict__ WoT) {
  long i = (long)blockIdx.x * blockDim.x + threadIdx.x;
  long stride = (long)gridDim.x * blockDim.x;
  const long n4 = (long)B_ * T_ * IN_ / 4;
  const float4* x4 = (const float4*)x;
  f16x4* o4 = (f16x4*)x16;
  for (long p = i; p < n4; p += stride) {
    float4 v = x4[p];
    f16x4 o = { (f16)v.x, (f16)v.y, (f16)v.z, (f16)v.w };
    o4[p] = o;
  }
  const long nw = (long)H_ * OUT_;
  for (long p = i; p < nw; p += stride) {
    long k = p / OUT_, c = p % OUT_;
    WoT[c * (long)H_ + k] = (f16)Wout[p];
  }
}

// 256 WGs x 256 threads. WG wg: group g = wg>>7 (batch rows g*32..g*32+31),
// wgi = wg&127 owns h-cols [wgi*8, wgi*8+8) i.e. gate cols {gt*1024 + wgi*8 + j}.
// 4 waves K-split over K=1536 (x: 128/wave, h: 256/wave).
__global__ __launch_bounds__(256, 1) void lstm_main(
    const float* __restrict__ W, const float* __restrict__ b,
    const f16* __restrict__ x16, f16* hbuf, unsigned int* flags) {

  const int wg   = blockIdx.x;
  const int g    = wg >> 7;
  const int wgi  = wg & 127;
  const int tid  = threadIdx.x;
  const int wave = tid >> 6;
  const int lane = tid & 63;

  const int hbase   = wgi * 8;
  const int colLane = lane & 31;        // MFMA N index (local col)
  const int khalf   = (lane >> 5) * 8;  // MFMA K sub-index
  const int arow    = lane & 31;        // MFMA M index (batch row in group)

  // ---- persistent W fragments (fp32 -> fp16, MFMA B layout) ----
  f16x8 wf[24];
  {
    const int gcol = (colLane >> 3) * H_ + hbase + (colLane & 7);
    #pragma unroll
    for (int f = 0; f < 24; ++f) {
      const int k0 = (f < 8) ? (128 * wave + 16 * f)
                             : (512 + 256 * wave + 16 * (f - 8));
      f16x8 v;
      #pragma unroll
      for (int j = 0; j < 8; ++j)
        v[j] = (f16)W[(long)(k0 + khalf + j) * G4_ + gcol];
      wf[f] = v;
    }
  }

  // epilogue ownership: thread -> (row erow, hcol offset ej)
  const int erow = tid >> 3;
  const int ej   = tid & 7;
  float bias[4];
  #pragma unroll
  for (int gt = 0; gt < 4; ++gt) bias[gt] = b[gt * H_ + hbase + ej];

  float c_state = 0.f;

  __shared__ float red[4][32][36];  // [wave][row][col], padded vs bank conflicts

  const f16* xg   = x16 + (long)(g * 32) * T_ * IN_;
  f16* hb         = hbuf + (long)g * 2 * 32 * H_;   // [2][32][1024]
  unsigned int* flg = flags + g * 128;              // 128 words = 8 lines

  // ---- x-part of t=0 (h0 = 0 is pre-zeroed in ws) ----
  f32x16 acc = {};
  {
    const f16* xrow = xg + (long)arow * (T_ * IN_) + 128 * wave + khalf;
    f16x8 xa[8];
    #pragma unroll
    for (int f = 0; f < 8; ++f) xa[f] = *(const f16x8*)(xrow + 16 * f);
    #pragma unroll
    for (int f = 0; f < 8; ++f)
      acc = __builtin_amdgcn_mfma_f32_32x32x16_f16(xa[f], wf[f], acc, 0, 0, 0);
  }

  for (int t = 0; t < T_; ++t) {
    // ---- wait: all 128 WGs of this group published h_t (flag >= t) ----
    // One polling wave per WG; lane l covers flags 2l,2l+1 via one u64 load.
    if (t > 0) {
      if (wave == 0) {
        const unsigned long long* f8 = (const unsigned long long*)flg;
        const unsigned int tgt = (unsigned int)t;
        long guard = 0;
        for (;;) {
          unsigned long long v = __hip_atomic_load(&f8[lane], __ATOMIC_RELAXED,
                                                   __HIP_MEMORY_SCOPE_AGENT);
          int ok = ((unsigned int)v >= tgt) && ((unsigned int)(v >> 32) >= tgt);
          if (__all(ok) || ++guard > (1L << 22)) break;
          __builtin_amdgcn_s_sleep(2);   // ~128 cyc backoff, decongest the lines
        }
      }
      __syncthreads();   // broadcast detection to waves 1..3
    }

    // ---- h-part (agent-coherent loads of h_t) ----
    {
      const f16* hrow = hb + (long)(t & 1) * (32 * H_) + (long)arow * H_
                           + 256 * wave + khalf;
      f16x8 ha[16];
      #pragma unroll
      for (int f = 0; f < 16; ++f)
        ha[f] = ld_agent_b128(hrow + 16 * f);
      wait_vm0();
      #pragma unroll
      for (int f = 0; f < 16; ++f)
        acc = __builtin_amdgcn_mfma_f32_32x32x16_f16(ha[f], wf[8 + f], acc, 0, 0, 0);
    }

    // ---- cross-wave K-reduction via LDS ----
    // C layout (32x32): col = lane&31, row = (reg&3) + 8*(reg>>2) + 4*(lane>>5)
    #pragma unroll
    for (int r = 0; r < 16; ++r) {
      const int row = (r & 3) + 8 * (r >> 2) + 4 * (lane >> 5);
      red[wave][row][colLane] = acc[r];
    }
    __syncthreads();

    // ---- epilogue: gates, c/h update, h store (write-through, ack later) ----
    float f4[4];
    #pragma unroll
    for (int gt = 0; gt < 4; ++gt) {
      float s = bias[gt];
      #pragma unroll
      for (int w = 0; w < 4; ++w) s += red[w][erow][gt * 8 + ej];
      f4[gt] = s;
    }
    const float fg = sigmoidf_(f4[0]);
    const float ig = sigmoidf_(f4[1]);
    const float gg = tanhf_(f4[2]);
    const float og = sigmoidf_(f4[3]);
    c_state = c_state * fg + ig * gg;
    const float hv = og * tanhf_(c_state);
    st_agent_b16(&hb[(long)((t + 1) & 1) * (32 * H_) + (long)erow * H_ + hbase + ej],
                 (f16)hv);

    // ---- next step's x-part while the h-store is in flight ----
    f32x16 accN = {};
    if (t + 1 < T_) {
      const f16* xrow = xg + (long)arow * (T_ * IN_) + (long)(t + 1) * IN_
                           + 128 * wave + khalf;
      f16x8 xa[8];
      #pragma unroll
      for (int f = 0; f < 8; ++f) xa[f] = *(const f16x8*)(xrow + 16 * f);
      #pragma unroll
      for (int f = 0; f < 8; ++f)
        accN = __builtin_amdgcn_mfma_f32_32x32x16_f16(xa[f], wf[f], accN, 0, 0, 0);
    }

    // ---- release: h stores acked at LLC, then one flag store per WG ----
    wait_vm0();
    __syncthreads();
    if (tid == 0)
      __hip_atomic_store(&flg[wgi], (unsigned int)(t + 1),
                         __ATOMIC_RELAXED, __HIP_MEMORY_SCOPE_AGENT);
    acc = accN;
  }
}

// out = h_T @ W_out + b_out : [64,1024]@[1024,512]. h_T is in h buf 0 (T even).
// 128 WGs: 4 row-tiles x 32 col-tiles of 16x16; 4 waves K-split 256 each.
__global__ __launch_bounds__(256) void lstm_out(
    const f16* __restrict__ hbuf, const f16* __restrict__ WoT,
    const float* __restrict__ bout, float* __restrict__ out) {
  const int wgid = blockIdx.x;
  const int rowT = wgid >> 5;   // 0..3
  const int colT = wgid & 31;   // 0..31
  const int tid  = threadIdx.x;
  const int wave = tid >> 6;
  const int lane = tid & 63;
  const int r16  = lane & 15;
  const int ksel = (lane >> 4) * 8;

  const int g = rowT >> 1;
  const f16* hrow = hbuf + (long)g * 2 * 32 * H_            // group base (buf 0)
                  + (long)((rowT & 1) * 16 + r16) * H_;
  const f16* wrow = WoT + (long)(colT * 16 + r16) * H_;

  f32x4 acc = {};
  #pragma unroll
  for (int f = 0; f < 8; ++f) {
    f16x8 a  = *(const f16x8*)(hrow + 256 * wave + 32 * f + ksel);
    f16x8 bf = *(const f16x8*)(wrow + 256 * wave + 32 * f + ksel);
    acc = __builtin_amdgcn_mfma_f32_16x16x32_f16(a, bf, acc, 0, 0, 0);
  }

  __shared__ float red[4][16][20];
  #pragma unroll
  for (int r = 0; r < 4; ++r)
    red[wave][(lane >> 4) * 4 + r][lane & 15] = acc[r];
  __syncthreads();

  const int row = tid >> 4;   // 0..15
  const int col = tid & 15;
  float s = bout[colT * 16 + col];
  #pragma unroll
  for (int w = 0; w < 4; ++w) s += red[w][row][col];
  out[(long)(rowT * 16 + row) * OUT_ + colT * 16 + col] = s;
}

extern "C" void kernel_launch(void* const* d_in, const int* in_sizes, int n_in,
                              void* d_out, int out_size, void* d_ws, size_t ws_size,
                              hipStream_t stream) {
  const float* x    = (const float*)d_in[0];
  const float* W    = (const float*)d_in[1];
  const float* b    = (const float*)d_in[2];
  const float* Wout = (const float*)d_in[3];
  const float* bout = (const float*)d_in[4];
  float* out = (float*)d_out;

  if (ws_size < WS_NEED) return;  // avoid corrupting memory if ws too small

  char* wsb = (char*)d_ws;
  f16* x16  = (f16*)(wsb + X16_OFF);
  f16* WoT  = (f16*)(wsb + WOT_OFF);
  f16* hbuf = (f16*)(wsb + H_OFF);
  unsigned int* flags = (unsigned int*)(wsb + FLG_OFF);

  // zero h double-buffers (h0 = 0) and flags
  hipMemsetAsync(wsb + H_OFF, 0, ZERO_BYTES, stream);

  lstm_prepass<<<1024, 256, 0, stream>>>(x, Wout, x16, WoT);

  // 256 WGs, 1 per CU.
  lstm_main<<<256, 256, 0, stream>>>(W, b, x16, hbuf, flags);

  lstm_out<<<128, 256, 0, stream>>>(hbuf, WoT, bout, out);
}

// Round 5
// 3577.866 us; speedup vs baseline: 1.0520x; 1.0520x over previous
//
#include <hip/hip_runtime.h>

// LSTM B=64 T=512 IN=512 H=1024 OUT=512, all fp32 in/out.
// Persistent-RNN: 256 WGs (2 groups x 128), W in VGPRs as fp16 MFMA fragments,
// h double-buffered in ws, agent-coherent (sc0 sc1) h traffic.
// R4 (back to R1 skeleton = 2490us best, + chain-shortening):
//   - per-wave producer-subset polling (32 flags/wave), no post-poll barrier
//   - single-wave release: LDS-gathered h, 32x 16B coalesced agent stores by
//     wave 0 only; ack overlapped with wave 0's next x-part; waves 1-3 free
//   - x-part never sits between h-store and flag publication

#define B_   64
#define T_   512
#define IN_  512
#define H_   1024
#define G4_  4096   // 4*H
#define OUT_ 512

typedef _Float16 f16;
typedef _Float16 f16x8 __attribute__((ext_vector_type(8)));
typedef _Float16 f16x4 __attribute__((ext_vector_type(4)));
typedef float f32x4  __attribute__((ext_vector_type(4)));
typedef float f32x16 __attribute__((ext_vector_type(16)));

// workspace layout (bytes)
#define X16_OFF   0UL                         // [64][512][512] f16 = 33554432
#define WOT_OFF   33554432UL                  // W_out^T [512][1024] f16 = 1048576
#define H_OFF     (WOT_OFF + 1048576UL)       // h: [2 grp][2 buf][32][1024] f16 = 262144
#define FLG_OFF   (H_OFF + 262144UL)          // flags: 2 groups x 128 u32
#define WS_NEED   (FLG_OFF + 2048UL)
#define ZERO_BYTES (262144UL + 2048UL)        // h + flags zeroed together

__device__ __forceinline__ float sigmoidf_(float v) { return 1.f / (1.f + __expf(-v)); }
__device__ __forceinline__ float tanhf_(float v) { return 1.f - 2.f / (__expf(2.f * v) + 1.f); }

// Agent-coherent 16B load: bypasses L1 (sc0) and the non-coherent per-XCD L2
// (sc1); served at the coherent LLC point.
__device__ __forceinline__ f16x8 ld_agent_b128(const f16* p) {
  f16x8 r;
  asm volatile("global_load_dwordx4 %0, %1, off sc0 sc1" : "=v"(r) : "v"(p));
  return r;
}

// Agent-coherent 16B store: write-through to the coherence point.
__device__ __forceinline__ void st_agent_b128(f16* p, f16x8 v) {
  asm volatile("global_store_dwordx4 %0, %1, off sc0 sc1" :: "v"(p), "v"(v) : "memory");
}

// Wait all outstanding VMEM; fence the scheduler so register-only MFMAs can't
// hoist above the wait (rule #18 hazard class).
__device__ __forceinline__ void wait_vm0() {
  asm volatile("s_waitcnt vmcnt(0)" ::: "memory");
  __builtin_amdgcn_sched_barrier(0);
}

__global__ __launch_bounds__(256) void lstm_prepass(
    const float* __restrict__ x, const float* __restrict__ Wout,
    f16* __restrict__ x16, f16* __restrict__ WoT) {
  long i = (long)blockIdx.x * blockDim.x + threadIdx.x;
  long stride = (long)gridDim.x * blockDim.x;
  const long n4 = (long)B_ * T_ * IN_ / 4;
  const float4* x4 = (const float4*)x;
  f16x4* o4 = (f16x4*)x16;
  for (long p = i; p < n4; p += stride) {
    float4 v = x4[p];
    f16x4 o = { (f16)v.x, (f16)v.y, (f16)v.z, (f16)v.w };
    o4[p] = o;
  }
  const long nw = (long)H_ * OUT_;
  for (long p = i; p < nw; p += stride) {
    long k = p / OUT_, c = p % OUT_;
    WoT[c * (long)H_ + k] = (f16)Wout[p];
  }
}

// 256 WGs x 256 threads. WG wg: group g = wg>>7 (batch rows g*32..g*32+31),
// wgi = wg&127 owns h-cols [wgi*8, wgi*8+8) i.e. gate cols {gt*1024 + wgi*8 + j}.
// 4 waves K-split over K=1536 (x: 128/wave, h: 256/wave).
// Wave w's h K-range [256w, 256w+256) is produced by WGs [32w, 32w+32).
__global__ __launch_bounds__(256, 2) void lstm_main(
    const float* __restrict__ W, const float* __restrict__ b,
    const f16* __restrict__ x16, f16* hbuf, unsigned int* flags) {

  const int wg   = blockIdx.x;
  const int g    = wg >> 7;
  const int wgi  = wg & 127;
  const int tid  = threadIdx.x;
  const int wave = tid >> 6;
  const int lane = tid & 63;

  const int hbase   = wgi * 8;
  const int colLane = lane & 31;        // MFMA N index (local col)
  const int khalf   = (lane >> 5) * 8;  // MFMA K sub-index
  const int arow    = lane & 31;        // MFMA M index (batch row in group)

  // ---- persistent W fragments (fp32 -> fp16, MFMA B layout) ----
  f16x8 wf[24];
  {
    const int gcol = (colLane >> 3) * H_ + hbase + (colLane & 7);
    #pragma unroll
    for (int f = 0; f < 24; ++f) {
      const int k0 = (f < 8) ? (128 * wave + 16 * f)
                             : (512 + 256 * wave + 16 * (f - 8));
      f16x8 v;
      #pragma unroll
      for (int j = 0; j < 8; ++j)
        v[j] = (f16)W[(long)(k0 + khalf + j) * G4_ + gcol];
      wf[f] = v;
    }
  }

  // epilogue ownership: thread -> (row erow, hcol offset ej)
  const int erow = tid >> 3;
  const int ej   = tid & 7;
  float bias[4];
  #pragma unroll
  for (int gt = 0; gt < 4; ++gt) bias[gt] = b[gt * H_ + hbase + ej];

  float c_state = 0.f;

  __shared__ float red[4][32][36];  // [wave][row][col], padded vs bank conflicts
  __shared__ f16 hshare[32][8];     // epilogue h gather (16B per row)

  const f16* xg   = x16 + (long)(g * 32) * T_ * IN_;
  f16* hb         = hbuf + (long)g * 2 * 32 * H_;   // [2][32][1024]
  unsigned int* flg = flags + g * 128;              // this group's 128 flags

  // ---- x-part of t=0 (h0 = 0 is pre-zeroed in ws) ----
  f32x16 acc = {};
  {
    const f16* xrow = xg + (long)arow * (T_ * IN_) + 128 * wave + khalf;
    f16x8 xa[8];
    #pragma unroll
    for (int f = 0; f < 8; ++f) xa[f] = *(const f16x8*)(xrow + 16 * f);
    #pragma unroll
    for (int f = 0; f < 8; ++f)
      acc = __builtin_amdgcn_mfma_f32_32x32x16_f16(xa[f], wf[f], acc, 0, 0, 0);
  }

  for (int t = 0; t < T_; ++t) {
    // ---- wait: MY producers (32 WGs for this wave's K-range) flagged t ----
    if (t > 0) {
      const unsigned int tgt = (unsigned int)t;
      volatile const unsigned int* fp = &flg[32 * wave + (lane & 31)];
      long guard = 0;
      for (;;) {
        unsigned int v = __hip_atomic_load((const unsigned int*)fp,
                                           __ATOMIC_RELAXED, __HIP_MEMORY_SCOPE_AGENT);
        if (__all(v >= tgt) || ++guard > (1L << 22)) break;
      }
    }

    // ---- h-part (agent-coherent loads of h_t) ----
    {
      const f16* hrow = hb + (long)(t & 1) * (32 * H_) + (long)arow * H_
                           + 256 * wave + khalf;
      f16x8 ha[16];
      #pragma unroll
      for (int f = 0; f < 16; ++f)
        ha[f] = ld_agent_b128(hrow + 16 * f);
      wait_vm0();
      #pragma unroll
      for (int f = 0; f < 16; ++f)
        acc = __builtin_amdgcn_mfma_f32_32x32x16_f16(ha[f], wf[8 + f], acc, 0, 0, 0);
    }

    // ---- cross-wave K-reduction via LDS ----
    // C layout (32x32): col = lane&31, row = (reg&3) + 8*(reg>>2) + 4*(lane>>5)
    #pragma unroll
    for (int r = 0; r < 16; ++r) {
      const int row = (r & 3) + 8 * (r >> 2) + 4 * (lane >> 5);
      red[wave][row][colLane] = acc[r];
    }
    __syncthreads();   // (A) red complete

    // ---- epilogue: gates, c/h update -> LDS gather buffer ----
    float f4[4];
    #pragma unroll
    for (int gt = 0; gt < 4; ++gt) {
      float s = bias[gt];
      #pragma unroll
      for (int w = 0; w < 4; ++w) s += red[w][erow][gt * 8 + ej];
      f4[gt] = s;
    }
    const float fg = sigmoidf_(f4[0]);
    const float ig = sigmoidf_(f4[1]);
    const float gg = tanhf_(f4[2]);
    const float og = sigmoidf_(f4[3]);
    c_state = c_state * fg + ig * gg;
    hshare[erow][ej] = (f16)(og * tanhf_(c_state));
    __syncthreads();   // (B) hshare ready; red fully consumed

    // ---- wave 0: issue 32 coalesced 16B agent stores of h_{t+1} ----
    if (wave == 0 && lane < 32) {
      f16x8 hv8 = *(const f16x8*)&hshare[lane][0];
      st_agent_b128(&hb[(long)((t + 1) & 1) * (32 * H_) + (long)lane * H_ + hbase], hv8);
    }

    // ---- next step's x-part (all waves; overlaps wave 0's store-ack) ----
    acc = f32x16{};
    if (t + 1 < T_) {
      const f16* xrow = xg + (long)arow * (T_ * IN_) + (long)(t + 1) * IN_
                           + 128 * wave + khalf;
      f16x8 xa[8];
      #pragma unroll
      for (int f = 0; f < 8; ++f) xa[f] = *(const f16x8*)(xrow + 16 * f);
      #pragma unroll
      for (int f = 0; f < 8; ++f)
        acc = __builtin_amdgcn_mfma_f32_32x32x16_f16(xa[f], wf[f], acc, 0, 0, 0);
    }

    // ---- wave 0: publish (stores acked at LLC by now or shortly) ----
    if (wave == 0) {
      wait_vm0();
      if (lane == 0)
        __hip_atomic_store(&flg[wgi], (unsigned int)(t + 1),
                           __ATOMIC_RELAXED, __HIP_MEMORY_SCOPE_AGENT);
    }
  }
}

// out = h_T @ W_out + b_out : [64,1024]@[1024,512]. h_T is in h buf 0 (T even).
// 128 WGs: 4 row-tiles x 32 col-tiles of 16x16; 4 waves K-split 256 each.
__global__ __launch_bounds__(256) void lstm_out(
    const f16* __restrict__ hbuf, const f16* __restrict__ WoT,
    const float* __restrict__ bout, float* __restrict__ out) {
  const int wgid = blockIdx.x;
  const int rowT = wgid >> 5;   // 0..3
  const int colT = wgid & 31;   // 0..31
  const int tid  = threadIdx.x;
  const int wave = tid >> 6;
  const int lane = tid & 63;
  const int r16  = lane & 15;
  const int ksel = (lane >> 4) * 8;

  const int g = rowT >> 1;
  const f16* hrow = hbuf + (long)g * 2 * 32 * H_            // group base (buf 0)
                  + (long)((rowT & 1) * 16 + r16) * H_;
  const f16* wrow = WoT + (long)(colT * 16 + r16) * H_;

  f32x4 acc = {};
  #pragma unroll
  for (int f = 0; f < 8; ++f) {
    f16x8 a  = *(const f16x8*)(hrow + 256 * wave + 32 * f + ksel);
    f16x8 bf = *(const f16x8*)(wrow + 256 * wave + 32 * f + ksel);
    acc = __builtin_amdgcn_mfma_f32_16x16x32_f16(a, bf, acc, 0, 0, 0);
  }

  __shared__ float red[4][16][20];
  #pragma unroll
  for (int r = 0; r < 4; ++r)
    red[wave][(lane >> 4) * 4 + r][lane & 15] = acc[r];
  __syncthreads();

  const int row = tid >> 4;   // 0..15
  const int col = tid & 15;
  float s = bout[colT * 16 + col];
  #pragma unroll
  for (int w = 0; w < 4; ++w) s += red[w][row][col];
  out[(long)(rowT * 16 + row) * OUT_ + colT * 16 + col] = s;
}

extern "C" void kernel_launch(void* const* d_in, const int* in_sizes, int n_in,
                              void* d_out, int out_size, void* d_ws, size_t ws_size,
                              hipStream_t stream) {
  const float* x    = (const float*)d_in[0];
  const float* W    = (const float*)d_in[1];
  const float* b    = (const float*)d_in[2];
  const float* Wout = (const float*)d_in[3];
  const float* bout = (const float*)d_in[4];
  float* out = (float*)d_out;

  if (ws_size < WS_NEED) return;  // avoid corrupting memory if ws too small

  char* wsb = (char*)d_ws;
  f16* x16  = (f16*)(wsb + X16_OFF);
  f16* WoT  = (f16*)(wsb + WOT_OFF);
  f16* hbuf = (f16*)(wsb + H_OFF);
  unsigned int* flags = (unsigned int*)(wsb + FLG_OFF);

  // zero h double-buffers (h0 = 0) and flags
  hipMemsetAsync(wsb + H_OFF, 0, ZERO_BYTES, stream);

  lstm_prepass<<<1024, 256, 0, stream>>>(x, Wout, x16, WoT);

  // 256 WGs, >=2 fit per CU -> all co-resident.
  lstm_main<<<256, 256, 0, stream>>>(W, b, x16, hbuf, flags);

  lstm_out<<<128, 256, 0, stream>>>(hbuf, WoT, bout, out);
}

// Round 6
// 2450.373 us; speedup vs baseline: 1.5361x; 1.4601x over previous
//
#include <hip/hip_runtime.h>

// LSTM B=64 T=512 IN=512 H=1024 OUT=512, all fp32 in/out.
// Persistent-RNN. R5: 2 groups x 64 WGs x 512 threads (8 waves), 16 h-cols/WG.
//  - halves the per-step h broadcast (8MB vs 16MB), halves barrier fan-in
//  - per-wave producer-subset polling (8 flags), flags 1-per-64B-line
//  - release: LDS gather -> wave0 coalesced agent stores -> vmcnt(0) -> flag,
//    with NOTHING between store and publish (R3/R4 bug fixed); x-part after.

#define B_   64
#define T_   512
#define IN_  512
#define H_   1024
#define G4_  4096   // 4*H
#define OUT_ 512

typedef _Float16 f16;
typedef _Float16 f16x8 __attribute__((ext_vector_type(8)));
typedef _Float16 f16x4 __attribute__((ext_vector_type(4)));
typedef float f32x4  __attribute__((ext_vector_type(4)));
typedef float f32x16 __attribute__((ext_vector_type(16)));

// workspace layout (bytes)
#define X16_OFF   0UL                         // [64][512][512] f16 = 33554432
#define WOT_OFF   33554432UL                  // W_out^T [512][1024] f16 = 1048576
#define H_OFF     (WOT_OFF + 1048576UL)       // h: [2 grp][2 buf][32][1024] f16 = 262144
#define FLG_OFF   (H_OFF + 262144UL)          // flags: 2 grp x 64 x 16 u32 = 8192
#define WS_NEED   (FLG_OFF + 8192UL)
#define ZERO_BYTES (262144UL + 8192UL)        // h + flags zeroed together

__device__ __forceinline__ float sigmoidf_(float v) { return 1.f / (1.f + __expf(-v)); }
__device__ __forceinline__ float tanhf_(float v) { return 1.f - 2.f / (__expf(2.f * v) + 1.f); }

// Agent-coherent 16B load: bypasses L1 (sc0) and non-coherent per-XCD L2 (sc1).
__device__ __forceinline__ f16x8 ld_agent_b128(const f16* p) {
  f16x8 r;
  asm volatile("global_load_dwordx4 %0, %1, off sc0 sc1" : "=v"(r) : "v"(p));
  return r;
}

// Agent-coherent 16B store: write-through to the coherence point.
__device__ __forceinline__ void st_agent_b128(f16* p, f16x8 v) {
  asm volatile("global_store_dwordx4 %0, %1, off sc0 sc1" :: "v"(p), "v"(v) : "memory");
}

// Wait all outstanding VMEM; fence the scheduler so register-only MFMAs can't
// hoist above the wait (rule #18 hazard class).
__device__ __forceinline__ void wait_vm0() {
  asm volatile("s_waitcnt vmcnt(0)" ::: "memory");
  __builtin_amdgcn_sched_barrier(0);
}

__global__ __launch_bounds__(256) void lstm_prepass(
    const float* __restrict__ x, const float* __restrict__ Wout,
    f16* __restrict__ x16, f16* __restrict__ WoT) {
  long i = (long)blockIdx.x * blockDim.x + threadIdx.x;
  long stride = (long)gridDim.x * blockDim.x;
  const long n4 = (long)B_ * T_ * IN_ / 4;
  const float4* x4 = (const float4*)x;
  f16x4* o4 = (f16x4*)x16;
  for (long p = i; p < n4; p += stride) {
    float4 v = x4[p];
    f16x4 o = { (f16)v.x, (f16)v.y, (f16)v.z, (f16)v.w };
    o4[p] = o;
  }
  const long nw = (long)H_ * OUT_;
  for (long p = i; p < nw; p += stride) {
    long k = p / OUT_, c = p % OUT_;
    WoT[c * (long)H_ + k] = (f16)Wout[p];
  }
}

// 128 WGs x 512 threads (8 waves). WG wg: group g = wg>>6 (rows g*32..g*32+31),
// wgi = wg&63 owns h-cols [wgi*16, wgi*16+16) -> 64 gate cols (2 N-tiles of 32).
// 8 waves K-split over K=1536: x 64/wave, h 128/wave.
// Wave w's h K-range [128w,128w+128) is produced by WGs [8w, 8w+8).
__global__ __launch_bounds__(512, 2) void lstm_main(
    const float* __restrict__ W, const float* __restrict__ b,
    const f16* __restrict__ x16, f16* hbuf, unsigned int* flags) {

  const int wg   = blockIdx.x;
  const int g    = wg >> 6;
  const int wgi  = wg & 63;
  const int tid  = threadIdx.x;
  const int wave = tid >> 6;    // 0..7
  const int lane = tid & 63;

  const int hbase   = wgi * 16;
  const int colLane = lane & 31;        // MFMA N index within tile
  const int khalf   = (lane >> 5) * 8;  // MFMA K sub-index
  const int arow    = lane & 31;        // MFMA M index (batch row in group)

  // ---- persistent W fragments (fp32 -> fp16, MFMA B layout) ----
  // frag f = n*12 + kf: N-tile n in {0,1}; kf<4 = x (k0=64w+16kf),
  // kf in [4,12) = h (k0=512+128w+16(kf-4)). Local col c = n*32+colLane:
  // gate = c>>4, hcol = hbase + (c&15).
  f16x8 wf[24];
  #pragma unroll
  for (int n = 0; n < 2; ++n) {
    const int gate = n * 2 + (colLane >> 4);
    const int gcol = gate * H_ + hbase + (colLane & 15);
    #pragma unroll
    for (int kf = 0; kf < 12; ++kf) {
      const int k0 = (kf < 4) ? (64 * wave + 16 * kf)
                              : (512 + 128 * wave + 16 * (kf - 4));
      f16x8 v;
      #pragma unroll
      for (int j = 0; j < 8; ++j)
        v[j] = (f16)W[(long)(k0 + khalf + j) * G4_ + gcol];
      wf[n * 12 + kf] = v;
    }
  }

  // epilogue ownership: thread -> (row erow 0..31, col offset ej 0..15)
  const int erow = tid >> 4;
  const int ej   = tid & 15;
  float bias[4];
  #pragma unroll
  for (int gt = 0; gt < 4; ++gt) bias[gt] = b[gt * H_ + hbase + ej];

  float c_state = 0.f;

  __shared__ float red[8][32][68];  // [wave][row][64 cols + pad]
  __shared__ f16 hshare[32][16];    // epilogue h gather

  const f16* xg   = x16 + (long)(g * 32) * T_ * IN_;
  f16* hb         = hbuf + (long)g * 2 * 32 * H_;   // [2][32][1024]
  unsigned int* flg = flags + g * 64 * 16;          // 64 flags, 64B apart

  // ---- x-part of t=0 (h0 = 0 pre-zeroed in ws) ----
  f32x16 acc0 = {}, acc1 = {};
  {
    const f16* xrow = xg + (long)arow * (T_ * IN_) + 64 * wave + khalf;
    f16x8 xa[4];
    #pragma unroll
    for (int f = 0; f < 4; ++f) xa[f] = *(const f16x8*)(xrow + 16 * f);
    #pragma unroll
    for (int kf = 0; kf < 4; ++kf) {
      acc0 = __builtin_amdgcn_mfma_f32_32x32x16_f16(xa[kf], wf[kf],      acc0, 0, 0, 0);
      acc1 = __builtin_amdgcn_mfma_f32_32x32x16_f16(xa[kf], wf[12 + kf], acc1, 0, 0, 0);
    }
  }

  for (int t = 0; t < T_; ++t) {
    // ---- wait: MY 8 producers (WGs 8w..8w+7) flagged t ----
    if (t > 0) {
      const unsigned int tgt = (unsigned int)t;
      const unsigned int* fp = &flg[(8 * wave + (lane & 7)) << 4];
      long guard = 0;
      for (;;) {
        unsigned int v = __hip_atomic_load(fp, __ATOMIC_RELAXED,
                                           __HIP_MEMORY_SCOPE_AGENT);
        if (__all(v >= tgt) || ++guard > (1L << 22)) break;
      }
    }

    // ---- h-part: agent-coherent loads of my K-range of h_t ----
    {
      const f16* hrow = hb + (long)(t & 1) * (32 * H_) + (long)arow * H_
                           + 128 * wave + khalf;
      f16x8 ha[8];
      #pragma unroll
      for (int f = 0; f < 8; ++f)
        ha[f] = ld_agent_b128(hrow + 16 * f);
      wait_vm0();
      #pragma unroll
      for (int kf = 0; kf < 8; ++kf) {
        acc0 = __builtin_amdgcn_mfma_f32_32x32x16_f16(ha[kf], wf[4 + kf],  acc0, 0, 0, 0);
        acc1 = __builtin_amdgcn_mfma_f32_32x32x16_f16(ha[kf], wf[16 + kf], acc1, 0, 0, 0);
      }
    }

    // ---- cross-wave K-reduction via LDS ----
    // C layout (32x32): col = lane&31, row = (r&3) + 8*(r>>2) + 4*(lane>>5)
    #pragma unroll
    for (int r = 0; r < 16; ++r) {
      const int row = (r & 3) + 8 * (r >> 2) + 4 * (lane >> 5);
      red[wave][row][colLane]      = acc0[r];
      red[wave][row][32 + colLane] = acc1[r];
    }
    __syncthreads();   // (A) red complete

    // ---- epilogue: gates, c/h update -> LDS gather ----
    float f4[4];
    #pragma unroll
    for (int gt = 0; gt < 4; ++gt) {
      float s = bias[gt];
      #pragma unroll
      for (int w = 0; w < 8; ++w) s += red[w][erow][gt * 16 + ej];
      f4[gt] = s;
    }
    const float fg = sigmoidf_(f4[0]);
    const float ig = sigmoidf_(f4[1]);
    const float gg = tanhf_(f4[2]);
    const float og = sigmoidf_(f4[3]);
    c_state = c_state * fg + ig * gg;
    hshare[erow][ej] = (f16)(og * tanhf_(c_state));
    __syncthreads();   // (B) hshare ready; red consumed

    // ---- wave 0: coalesced agent stores of h_{t+1}, then IMMEDIATE publish --
    if (wave == 0) {
      const int row = lane >> 1, half = lane & 1;
      f16x8 hv = *(const f16x8*)&hshare[row][half * 8];
      st_agent_b128(&hb[(long)((t + 1) & 1) * (32 * H_) + (long)row * H_
                        + hbase + half * 8], hv);
      wait_vm0();
      if (lane == 0)
        __hip_atomic_store(&flg[wgi << 4], (unsigned int)(t + 1),
                           __ATOMIC_RELAXED, __HIP_MEMORY_SCOPE_AGENT);
    }

    // ---- next step's x-part (after publish; never delays it) ----
    acc0 = f32x16{}; acc1 = f32x16{};
    if (t + 1 < T_) {
      const f16* xrow = xg + (long)arow * (T_ * IN_) + (long)(t + 1) * IN_
                           + 64 * wave + khalf;
      f16x8 xa[4];
      #pragma unroll
      for (int f = 0; f < 4; ++f) xa[f] = *(const f16x8*)(xrow + 16 * f);
      #pragma unroll
      for (int kf = 0; kf < 4; ++kf) {
        acc0 = __builtin_amdgcn_mfma_f32_32x32x16_f16(xa[kf], wf[kf],      acc0, 0, 0, 0);
        acc1 = __builtin_amdgcn_mfma_f32_32x32x16_f16(xa[kf], wf[12 + kf], acc1, 0, 0, 0);
      }
    }
  }
}

// out = h_T @ W_out + b_out : [64,1024]@[1024,512]. h_T is in h buf 0 (T even).
// 128 WGs: 4 row-tiles x 32 col-tiles of 16x16; 4 waves K-split 256 each.
__global__ __launch_bounds__(256) void lstm_out(
    const f16* __restrict__ hbuf, const f16* __restrict__ WoT,
    const float* __restrict__ bout, float* __restrict__ out) {
  const int wgid = blockIdx.x;
  const int rowT = wgid >> 5;   // 0..3
  const int colT = wgid & 31;   // 0..31
  const int tid  = threadIdx.x;
  const int wave = tid >> 6;
  const int lane = tid & 63;
  const int r16  = lane & 15;
  const int ksel = (lane >> 4) * 8;

  const int g = rowT >> 1;
  const f16* hrow = hbuf + (long)g * 2 * 32 * H_            // group base (buf 0)
                  + (long)((rowT & 1) * 16 + r16) * H_;
  const f16* wrow = WoT + (long)(colT * 16 + r16) * H_;

  f32x4 acc = {};
  #pragma unroll
  for (int f = 0; f < 8; ++f) {
    f16x8 a  = *(const f16x8*)(hrow + 256 * wave + 32 * f + ksel);
    f16x8 bf = *(const f16x8*)(wrow + 256 * wave + 32 * f + ksel);
    acc = __builtin_amdgcn_mfma_f32_16x16x32_f16(a, bf, acc, 0, 0, 0);
  }

  __shared__ float red[4][16][20];
  #pragma unroll
  for (int r = 0; r < 4; ++r)
    red[wave][(lane >> 4) * 4 + r][lane & 15] = acc[r];
  __syncthreads();

  const int row = tid >> 4;   // 0..15
  const int col = tid & 15;
  float s = bout[colT * 16 + col];
  #pragma unroll
  for (int w = 0; w < 4; ++w) s += red[w][row][col];
  out[(long)(rowT * 16 + row) * OUT_ + colT * 16 + col] = s;
}

extern "C" void kernel_launch(void* const* d_in, const int* in_sizes, int n_in,
                              void* d_out, int out_size, void* d_ws, size_t ws_size,
                              hipStream_t stream) {
  const float* x    = (const float*)d_in[0];
  const float* W    = (const float*)d_in[1];
  const float* b    = (const float*)d_in[2];
  const float* Wout = (const float*)d_in[3];
  const float* bout = (const float*)d_in[4];
  float* out = (float*)d_out;

  if (ws_size < WS_NEED) return;  // avoid corrupting memory if ws too small

  char* wsb = (char*)d_ws;
  f16* x16  = (f16*)(wsb + X16_OFF);
  f16* WoT  = (f16*)(wsb + WOT_OFF);
  f16* hbuf = (f16*)(wsb + H_OFF);
  unsigned int* flags = (unsigned int*)(wsb + FLG_OFF);

  // zero h double-buffers (h0 = 0) and flags
  hipMemsetAsync(wsb + H_OFF, 0, ZERO_BYTES, stream);

  lstm_prepass<<<1024, 256, 0, stream>>>(x, Wout, x16, WoT);

  // 128 WGs x 512 threads, 1 per CU.
  lstm_main<<<128, 512, 0, stream>>>(W, b, x16, hbuf, flags);

  lstm_out<<<128, 256, 0, stream>>>(hbuf, WoT, bout, out);
}